// Round 2
// baseline (82.015 us; speedup 1.0000x reference)
//
#include <hip/hip_runtime.h>

#define D 128
#define NS 16
#define BATCH 16384
#define CHUNK 256
#define TILE 32
#define PST 40  // prep LDS row stride (shorts): 16B-aligned, decent bank spread

typedef __attribute__((ext_vector_type(8))) short short8;
typedef __attribute__((ext_vector_type(4))) float f32x4;

__device__ __forceinline__ unsigned short f2bf(float f) {
  unsigned u = __builtin_bit_cast(unsigned, f);
  u += 0x7FFFu + ((u >> 16) & 1u);   // round-to-nearest-even
  return (unsigned short)(u >> 16);
}

__device__ __forceinline__ short8 pack8s(float4 a, float4 b) {
  unsigned short p[8];
  p[0] = f2bf(a.x); p[1] = f2bf(a.y); p[2] = f2bf(a.z); p[3] = f2bf(a.w);
  p[4] = f2bf(b.x); p[5] = f2bf(b.y); p[6] = f2bf(b.z); p[7] = f2bf(b.w);
  return *(const short8*)p;
}

// ---------------------------------------------------------------------------
// Kernel 0 (unchanged from R1): one-time weight prep.
// Wt[(mat*NS+s)*D*D + col*D + row] = bf16(M[s][row][col]) — TRANSPOSED so an
// MFMA B-fragment (8 consecutive k at fixed col) is one contiguous 16B load.
// ---------------------------------------------------------------------------
__global__ __launch_bounds__(256, 2) void prep_weights(
    const float* __restrict__ A_all, const float* __restrict__ C_all,
    unsigned short* __restrict__ Wt) {
  __shared__ unsigned short T[D * PST];  // [col][r_local(32)+pad]
  const int b = blockIdx.x;
  const int s = b >> 3, mat = (b >> 2) & 1, r0 = (b & 3) * 32;
  const float* __restrict__ src =
      (mat ? C_all : A_all) + (size_t)s * D * D + (size_t)r0 * D;
  unsigned short* __restrict__ dst = Wt + (size_t)(mat * NS + s) * D * D + r0;
  const int t = threadIdx.x;
  {
    const int r = t >> 3, c0 = (t & 7) * 16;  // 32 rows x 8 threads/row
    const float4* srow = (const float4*)(src + r * D + c0);
#pragma unroll
    for (int i = 0; i < 4; i++) {
      float4 v = srow[i];
      T[(c0 + i * 4 + 0) * PST + r] = f2bf(v.x);
      T[(c0 + i * 4 + 1) * PST + r] = f2bf(v.y);
      T[(c0 + i * 4 + 2) * PST + r] = f2bf(v.z);
      T[(c0 + i * 4 + 3) * PST + r] = f2bf(v.w);
    }
  }
  __syncthreads();
  {
    const int c = t >> 1, rh = (t & 1) * 16;  // 128 cols x 2 threads/col
    const uint4* tsrc = (const uint4*)&T[c * PST + rh];
    uint4* d4 = (uint4*)(dst + (size_t)c * D + rh);
    d4[0] = tsrc[0];
    d4[1] = tsrc[1];
  }
}

// ---------------------------------------------------------------------------
// Kernel 1, latency-focused rewrite (R2):
//  - CHUNK=256 -> 1024 blocks, 4 blocks/CU (4 waves/SIMD, was 2). TILE=32
//    matches E[cnt]=16..32 (was 64 with E[cnt]=32: half-empty tiles).
//  - NO X LDS staging: MFMA A-frag (row=lane&15, 8 contiguous k) is read
//    straight from global x as 2x float4 + bf16 pack. Per instruction a wave
//    covers 16 rows x 64B contiguous — clean coalescing; all 4 waves read the
//    same 16KB of rows -> L1 reuse.
//  - Barriers per tile: 2 (was 5). b1: wcnt ready. loop-top: rowlist ready /
//    prev-iter H reads done. b2: H ready. H has its own swizzled buffer (no
//    X/H aliasing -> no WAR barrier).
//  - cW (phase-2 weights) loaded AFTER phase 1 so peak VGPR fits 128
//    (__launch_bounds__(256,4)); L2 latency hides under H-stage + barrier.
//  MFMA 16x16x32 bf16 layouts (HW-verified):
//    A: A[m=lane&15][k=(lane>>4)*8+j]   B: B[k=(lane>>4)*8+j][n=lane&15]
//    C/D: col=lane&15, row=(lane>>4)*4+reg
//  LDS: H 8K + rowlist 1K + wcnt = 9.2K. Weights 32 VGPR per matrix per wave.
// ---------------------------------------------------------------------------
__global__ __launch_bounds__(256, 4) void ssm_mfma(
    const float* __restrict__ x,
    const int* __restrict__ sidx,
    const unsigned short* __restrict__ Wt,
    float* __restrict__ out) {
  __shared__ unsigned short H[TILE * D];  // [row][chunk ^ (row&15)][8]
  __shared__ int rowlist[CHUNK];
  __shared__ int wcnt[4];

  const int b = blockIdx.x;
  const int s = (b & 7) | (((b >> 3) & 1) << 3);  // same-state blocks same XCD
  const int c0 = (b >> 4) * CHUNK;
  const int tid = threadIdx.x;
  const int lane = tid & 63, w = tid >> 6;
  const int l15 = lane & 15, quad = lane >> 4;

  // ---- chunk scan load (1 value/thread; L2-resident after first iter) ----
  const int v0 = sidx[c0 + tid];

  // ---- phase-1 weights direct from Wt (L2): 8 frags = 32 VGPR ----
  const unsigned short* As =
      Wt + (size_t)s * D * D + (size_t)(w * 32 + l15) * D + quad * 8;
  short8 aW[4][2];
#pragma unroll
  for (int kb = 0; kb < 4; kb++)
#pragma unroll
    for (int nb = 0; nb < 2; nb++)
      aW[kb][nb] = *(const short8*)(As + nb * 16 * D + kb * 32);

  // ---- ballot compaction ----
  const unsigned long long lanelt = (1ull << lane) - 1ull;
  const unsigned long long m0 = __ballot(v0 == s);
  if (lane == 0) wcnt[w] = (int)__popcll(m0);
  __syncthreads();  // b1: wcnt ready
  int pre = 0, cnt = 0;
#pragma unroll
  for (int ww = 0; ww < 4; ww++) {
    if (ww < w) pre += wcnt[ww];
    cnt += wcnt[ww];
  }
  if (v0 == s) rowlist[pre + (int)__popcll(m0 & lanelt)] = c0 + tid;
  if (cnt == 0) return;  // block-uniform (and before the next barrier)

  // ---- tiles (cnt ~ Bin(256,1/16): one 32-row tile ~always) ----
#pragma unroll 1
  for (int i0 = 0; i0 < cnt; i0 += TILE) {
    __syncthreads();  // rowlist ready / previous-iter H reads done

    const int r0i = i0 + l15, r1i = i0 + 16 + l15;
    const int rid0 = (r0i < cnt) ? rowlist[r0i] : -1;
    const int rid1 = (r1i < cnt) ? rowlist[r1i] : -1;

    // phase 1: acc = relu-pending X @ A ; wave w owns cols w*32..+31
    f32x4 acc[2][2];
#pragma unroll
    for (int ti = 0; ti < 2; ti++)
#pragma unroll
      for (int nb = 0; nb < 2; nb++) acc[ti][nb] = (f32x4){0.f, 0.f, 0.f, 0.f};
#pragma unroll
    for (int kb = 0; kb < 4; kb++) {
      short8 a0 = {0, 0, 0, 0, 0, 0, 0, 0};
      short8 a1 = {0, 0, 0, 0, 0, 0, 0, 0};
      if (rid0 >= 0) {
        const float4* p = (const float4*)(x + (size_t)rid0 * D + kb * 32 + quad * 8);
        a0 = pack8s(p[0], p[1]);
      }
      if (rid1 >= 0) {
        const float4* p = (const float4*)(x + (size_t)rid1 * D + kb * 32 + quad * 8);
        a1 = pack8s(p[0], p[1]);
      }
#pragma unroll
      for (int nb = 0; nb < 2; nb++) {
        acc[0][nb] = __builtin_amdgcn_mfma_f32_16x16x32_bf16(a0, aW[kb][nb],
                                                             acc[0][nb], 0, 0, 0);
        acc[1][nb] = __builtin_amdgcn_mfma_f32_16x16x32_bf16(a1, aW[kb][nb],
                                                             acc[1][nb], 0, 0, 0);
      }
    }

    // phase-2 weights now (latency hides under H-stage + barrier)
    short8 cW[4][2];
    {
      const unsigned short* Cs = As + (size_t)NS * D * D;
#pragma unroll
      for (int kb = 0; kb < 4; kb++)
#pragma unroll
        for (int nb = 0; nb < 2; nb++)
          cW[kb][nb] = *(const short8*)(Cs + nb * 16 * D + kb * 32);
    }

    // H = relu(acc) -> LDS, chunk-XOR swizzled (chunk' = chunk ^ (row&15))
#pragma unroll
    for (int ti = 0; ti < 2; ti++)
#pragma unroll
      for (int nb = 0; nb < 2; nb++)
#pragma unroll
        for (int rr = 0; rr < 4; rr++) {
          float v = acc[ti][nb][rr];
          const int row = ti * 16 + quad * 4 + rr;
          const int ch = (w * 4 + nb * 2 + (l15 >> 3)) ^ (quad * 4 + rr);
          H[row * D + (ch << 3) + (l15 & 7)] = f2bf(v > 0.f ? v : 0.f);
        }
    __syncthreads();  // H ready

    // phase 2: out = H @ C
#pragma unroll
    for (int ti = 0; ti < 2; ti++)
#pragma unroll
      for (int nb = 0; nb < 2; nb++) acc[ti][nb] = (f32x4){0.f, 0.f, 0.f, 0.f};
#pragma unroll
    for (int kb = 0; kb < 4; kb++) {
      short8 aF[2];
#pragma unroll
      for (int ti = 0; ti < 2; ti++)
        aF[ti] = *(const short8*)&H[(ti * 16 + l15) * D +
                                    (((kb * 4 + quad) ^ l15) << 3)];
#pragma unroll
      for (int ti = 0; ti < 2; ti++) {
        acc[ti][0] = __builtin_amdgcn_mfma_f32_16x16x32_bf16(aF[ti], cW[kb][0],
                                                             acc[ti][0], 0, 0, 0);
        acc[ti][1] = __builtin_amdgcn_mfma_f32_16x16x32_bf16(aF[ti], cW[kb][1],
                                                             acc[ti][1], 0, 0, 0);
      }
    }

    // scatter stores (fp32; 16 consecutive lanes -> 64B segments)
#pragma unroll
    for (int ti = 0; ti < 2; ti++)
#pragma unroll
      for (int rr = 0; rr < 4; rr++) {
        const int rl = i0 + ti * 16 + quad * 4 + rr;
        if (rl < cnt) {
          float* orow = out + (size_t)rowlist[rl] * D + w * 32 + l15;
          orow[0] = acc[ti][0][rr];
          orow[16] = acc[ti][1][rr];
        }
      }
  }
}

extern "C" void kernel_launch(void* const* d_in, const int* in_sizes, int n_in,
                              void* d_out, int out_size, void* d_ws, size_t ws_size,
                              hipStream_t stream) {
  const float* x = (const float*)d_in[0];
  const int* sidx = (const int*)d_in[1];
  const float* A_all = (const float*)d_in[2];
  const float* C_all = (const float*)d_in[3];
  float* out = (float*)d_out;

  // Wt: 2*NS*D*D*2B = 1 MiB of workspace (rewritten every launch).
  unsigned short* Wt = (unsigned short*)d_ws;

  prep_weights<<<128, 256, 0, stream>>>(A_all, C_all, Wt);
  ssm_mfma<<<BATCH / CHUNK * NS, 256, 0, stream>>>(x, sidx, Wt, out);
}

// Round 3
// 77.588 us; speedup vs baseline: 1.0571x; 1.0571x over previous
//
#include <hip/hip_runtime.h>

#define D 128
#define NS 16
#define BATCH 16384
#define CHUNK 256
#define TILE 32
#define PST 40  // prep LDS row stride (shorts): 16B-aligned, decent bank spread

typedef __attribute__((ext_vector_type(8))) short short8;
typedef __attribute__((ext_vector_type(4))) float f32x4;

__device__ __forceinline__ unsigned short f2bf(float f) {
  unsigned u = __builtin_bit_cast(unsigned, f);
  u += 0x7FFFu + ((u >> 16) & 1u);   // round-to-nearest-even
  return (unsigned short)(u >> 16);
}

__device__ __forceinline__ uint4 pack8(float4 a, float4 b) {
  unsigned short p[8];
  p[0] = f2bf(a.x); p[1] = f2bf(a.y); p[2] = f2bf(a.z); p[3] = f2bf(a.w);
  p[4] = f2bf(b.x); p[5] = f2bf(b.y); p[6] = f2bf(b.z); p[7] = f2bf(b.w);
  return *(const uint4*)p;
}

// ---------------------------------------------------------------------------
// Kernel 0 (unchanged): one-time weight prep.
// Wt[(mat*NS+s)*D*D + col*D + row] = bf16(M[s][row][col]) — TRANSPOSED so an
// MFMA B-fragment (8 consecutive k at fixed col) is one contiguous 16B load.
// ---------------------------------------------------------------------------
__global__ __launch_bounds__(256, 2) void prep_weights(
    const float* __restrict__ A_all, const float* __restrict__ C_all,
    unsigned short* __restrict__ Wt) {
  __shared__ unsigned short T[D * PST];  // [col][r_local(32)+pad]
  const int b = blockIdx.x;
  const int s = b >> 3, mat = (b >> 2) & 1, r0 = (b & 3) * 32;
  const float* __restrict__ src =
      (mat ? C_all : A_all) + (size_t)s * D * D + (size_t)r0 * D;
  unsigned short* __restrict__ dst = Wt + (size_t)(mat * NS + s) * D * D + r0;
  const int t = threadIdx.x;
  {
    const int r = t >> 3, c0 = (t & 7) * 16;  // 32 rows x 8 threads/row
    const float4* srow = (const float4*)(src + r * D + c0);
#pragma unroll
    for (int i = 0; i < 4; i++) {
      float4 v = srow[i];
      T[(c0 + i * 4 + 0) * PST + r] = f2bf(v.x);
      T[(c0 + i * 4 + 1) * PST + r] = f2bf(v.y);
      T[(c0 + i * 4 + 2) * PST + r] = f2bf(v.z);
      T[(c0 + i * 4 + 3) * PST + r] = f2bf(v.w);
    }
  }
  __syncthreads();
  {
    const int c = t >> 1, rh = (t & 1) * 16;  // 128 cols x 2 threads/col
    const uint4* tsrc = (const uint4*)&T[c * PST + rh];
    uint4* d4 = (uint4*)(dst + (size_t)c * D + rh);
    d4[0] = tsrc[0];
    d4[1] = tsrc[1];
  }
}

// ---------------------------------------------------------------------------
// Kernel 1 (R3): isolates the occupancy lever.
//  vs R1: grid 512->1024 (CHUNK 256, TILE 32) => 4 waves/SIMD (was 2); tile
//         padding ~gone (E[cnt]=16, TILE=32 vs 64-tile at E[cnt]=32).
//  vs R2: X staged ONCE to LDS (coalesced, 8 thr/row) instead of 4x-redundant
//         per-wave global gathers (R2's regression suspect).
//  Kept: transposed bf16 Wt direct B-frags (L2), XOR-swizzled XH (0 bank
//        conflicts), 3 barriers/tile, cW deferred past phase 1 (VGPR<=~100).
//  MFMA 16x16x32 bf16 layouts (HW-verified):
//    A: A[m=lane&15][k=(lane>>4)*8+j]   B: B[k=(lane>>4)*8+j][n=lane&15]
//    C/D: col=lane&15, row=(lane>>4)*4+reg
//  LDS: XH 8K + rowlist 1K + wcnt = 9.2K -> 4 blocks/CU = 37K, fine.
// ---------------------------------------------------------------------------
__global__ __launch_bounds__(256, 4) void ssm_mfma(
    const float* __restrict__ x,
    const int* __restrict__ sidx,
    const unsigned short* __restrict__ Wt,
    float* __restrict__ out) {
  __shared__ unsigned short XH[TILE * D];  // [row][chunk ^ (row&15)][8]
  __shared__ int rowlist[CHUNK];
  __shared__ int wcnt[4];

  const int b = blockIdx.x;
  const int s = (b & 7) | (((b >> 3) & 1) << 3);  // same-state blocks same XCD
  const int c0 = (b >> 4) * CHUNK;
  const int tid = threadIdx.x;
  const int lane = tid & 63, w = tid >> 6;
  const int l15 = lane & 15, quad = lane >> 4;

  // ---- chunk scan load (1 value/thread) ----
  const int v0 = sidx[c0 + tid];

  // ---- phase-1 weights direct from Wt (L2): 8 frags = 32 VGPR ----
  const unsigned short* As =
      Wt + (size_t)s * D * D + (size_t)(w * 32 + l15) * D + quad * 8;
  short8 aW[4][2];
#pragma unroll
  for (int kb = 0; kb < 4; kb++)
#pragma unroll
    for (int nb = 0; nb < 2; nb++)
      aW[kb][nb] = *(const short8*)(As + nb * 16 * D + kb * 32);

  // ---- ballot compaction ----
  const unsigned long long lanelt = (1ull << lane) - 1ull;
  const unsigned long long m0 = __ballot(v0 == s);
  if (lane == 0) wcnt[w] = (int)__popcll(m0);
  __syncthreads();  // b1: wcnt ready
  int pre = 0, cnt = 0;
#pragma unroll
  for (int ww = 0; ww < 4; ww++) {
    if (ww < w) pre += wcnt[ww];
    cnt += wcnt[ww];
  }
  if (v0 == s) rowlist[pre + (int)__popcll(m0 & lanelt)] = c0 + tid;
  if (cnt == 0) return;  // block-uniform

  // ---- tiles (cnt ~ Bin(256,1/16), mean 16: one 32-row tile ~always) ----
#pragma unroll 1
  for (int i0 = 0; i0 < cnt; i0 += TILE) {
    __syncthreads();  // rowlist ready / previous-iter XH reads done

    // stage 32 X rows to LDS once (8 threads/row, 16 elems each), swizzled
    {
      const int r = tid >> 3, q8 = tid & 7;
      const int rid = (i0 + r < cnt) ? rowlist[i0 + r] : -1;
      const int cA = q8 * 2, cB = q8 * 2 + 1;
      uint4* dA = (uint4*)&XH[r * D + ((cA ^ (r & 15)) << 3)];
      uint4* dB = (uint4*)&XH[r * D + ((cB ^ (r & 15)) << 3)];
      if (rid >= 0) {
        const float4* p = (const float4*)(x + (size_t)rid * D + q8 * 16);
        *dA = pack8(p[0], p[1]);
        *dB = pack8(p[2], p[3]);
      } else {
        uint4 z = {0, 0, 0, 0};
        *dA = z;
        *dB = z;
      }
    }
    __syncthreads();  // X ready

    // phase 1: acc = X @ A ; wave w owns cols w*32..+31
    f32x4 acc[2][2];
#pragma unroll
    for (int ti = 0; ti < 2; ti++)
#pragma unroll
      for (int nb = 0; nb < 2; nb++) acc[ti][nb] = (f32x4){0.f, 0.f, 0.f, 0.f};
#pragma unroll
    for (int kb = 0; kb < 4; kb++) {
      short8 aF[2];
#pragma unroll
      for (int ti = 0; ti < 2; ti++)
        aF[ti] = *(const short8*)&XH[(ti * 16 + l15) * D +
                                     (((kb * 4 + quad) ^ l15) << 3)];
#pragma unroll
      for (int ti = 0; ti < 2; ti++) {
        acc[ti][0] = __builtin_amdgcn_mfma_f32_16x16x32_bf16(aF[ti], aW[kb][0],
                                                             acc[ti][0], 0, 0, 0);
        acc[ti][1] = __builtin_amdgcn_mfma_f32_16x16x32_bf16(aF[ti], aW[kb][1],
                                                             acc[ti][1], 0, 0, 0);
      }
    }

    // phase-2 weights now (latency hides under H-stage + barrier)
    short8 cW[4][2];
    {
      const unsigned short* Cs = As + (size_t)NS * D * D;
#pragma unroll
      for (int kb = 0; kb < 4; kb++)
#pragma unroll
        for (int nb = 0; nb < 2; nb++)
          cW[kb][nb] = *(const short8*)(Cs + nb * 16 * D + kb * 32);
    }

    __syncthreads();  // phase-1 XH(X) reads done (XH reused for H)

    // H = relu(acc) -> XH, chunk-XOR swizzled (chunk' = chunk ^ (row&15))
#pragma unroll
    for (int ti = 0; ti < 2; ti++)
#pragma unroll
      for (int nb = 0; nb < 2; nb++)
#pragma unroll
        for (int rr = 0; rr < 4; rr++) {
          float v = acc[ti][nb][rr];
          const int row = ti * 16 + quad * 4 + rr;
          const int ch = (w * 4 + nb * 2 + (l15 >> 3)) ^ (quad * 4 + rr);
          XH[row * D + (ch << 3) + (l15 & 7)] = f2bf(v > 0.f ? v : 0.f);
        }
    __syncthreads();  // H ready

    // phase 2: out = H @ C
#pragma unroll
    for (int ti = 0; ti < 2; ti++)
#pragma unroll
      for (int nb = 0; nb < 2; nb++) acc[ti][nb] = (f32x4){0.f, 0.f, 0.f, 0.f};
#pragma unroll
    for (int kb = 0; kb < 4; kb++) {
      short8 aF[2];
#pragma unroll
      for (int ti = 0; ti < 2; ti++)
        aF[ti] = *(const short8*)&XH[(ti * 16 + l15) * D +
                                     (((kb * 4 + quad) ^ l15) << 3)];
#pragma unroll
      for (int ti = 0; ti < 2; ti++) {
        acc[ti][0] = __builtin_amdgcn_mfma_f32_16x16x32_bf16(aF[ti], cW[kb][0],
                                                             acc[ti][0], 0, 0, 0);
        acc[ti][1] = __builtin_amdgcn_mfma_f32_16x16x32_bf16(aF[ti], cW[kb][1],
                                                             acc[ti][1], 0, 0, 0);
      }
    }

    // scatter stores (fp32; 16 consecutive lanes -> 64B segments)
#pragma unroll
    for (int ti = 0; ti < 2; ti++)
#pragma unroll
      for (int rr = 0; rr < 4; rr++) {
        const int rl = i0 + ti * 16 + quad * 4 + rr;
        if (rl < cnt) {
          float* orow = out + (size_t)rowlist[rl] * D + w * 32 + l15;
          orow[0] = acc[ti][0][rr];
          orow[16] = acc[ti][1][rr];
        }
      }
  }
}

extern "C" void kernel_launch(void* const* d_in, const int* in_sizes, int n_in,
                              void* d_out, int out_size, void* d_ws, size_t ws_size,
                              hipStream_t stream) {
  const float* x = (const float*)d_in[0];
  const int* sidx = (const int*)d_in[1];
  const float* A_all = (const float*)d_in[2];
  const float* C_all = (const float*)d_in[3];
  float* out = (float*)d_out;

  // Wt: 2*NS*D*D*2B = 1 MiB of workspace (rewritten every launch).
  unsigned short* Wt = (unsigned short*)d_ws;

  prep_weights<<<128, 256, 0, stream>>>(A_all, C_all, Wt);
  ssm_mfma<<<BATCH / CHUNK * NS, 256, 0, stream>>>(x, sidx, Wt, out);
}

// Round 5
// 71.924 us; speedup vs baseline: 1.1403x; 1.0788x over previous
//
#include <hip/hip_runtime.h>

#define D 128
#define NS 16
#define BATCH 16384
#define TILE 64
#define CHUNK 512

typedef __attribute__((ext_vector_type(8))) short short8;
typedef __attribute__((ext_vector_type(4))) float f32x4;

__device__ __forceinline__ unsigned short f2bf(float f) {
  unsigned u = __builtin_bit_cast(unsigned, f);
  u += 0x7FFFu + ((u >> 16) & 1u);   // round-to-nearest-even
  return (unsigned short)(u >> 16);
}

__device__ __forceinline__ uint4 pack8(float4 a, float4 b) {
  unsigned short p[8];
  p[0] = f2bf(a.x); p[1] = f2bf(a.y); p[2] = f2bf(a.z); p[3] = f2bf(a.w);
  p[4] = f2bf(b.x); p[5] = f2bf(b.y); p[6] = f2bf(b.z); p[7] = f2bf(b.w);
  return *(const uint4*)p;
}

// ---------------------------------------------------------------------------
// R5 = R0's single-kernel config (512 blocks, CHUNK 512, TILE 64, 2 blk/CU)
// with the weight path moved fully into registers:
//  - B-frags (A and C) gathered DIRECTLY from fp32 global into short8 regs:
//    per frag 8 coalesced dword loads (16 lanes x 4B = 64B segments, 4 rows).
//    Waves own disjoint 32-col slices -> each weight byte read once per block
//    (same 128KB/block as R0). No Ws LDS buffer, no staging writes, no 256
//    scalar ds_read_u16 per wave per pass, one fewer barrier.
//  - XH [64][128] chunk-XOR swizzled (ch' = ch ^ (row&15), 16B chunks) —
//    R3-validated; aF ds_read_b128 conflict-free (R0 was 8-way at stride 136).
//  MFMA 16x16x32 bf16 layouts (HW-verified):
//    A: A[m=lane&15][k=(lane>>4)*8+j]   B: B[k=(lane>>4)*8+j][n=lane&15]
//    C/D: col=lane&15, row=(lane>>4)*4+reg
//  Wave w: all 64 rows, cols w*32..+31. acc[4][2]=32 VGPR, aW+cW=64 VGPR;
//  peak ~150 VGPR, fine at 2 waves/SIMD (budget 256).
//  LDS: XH 16K + rowlist 2K + wcnt = 18.1K.
// ---------------------------------------------------------------------------
__global__ __launch_bounds__(256, 2) void ssm_fused(
    const float* __restrict__ x,
    const int* __restrict__ sidx,
    const float* __restrict__ A_all,
    const float* __restrict__ C_all,
    float* __restrict__ out) {
  __shared__ unsigned short XH[TILE * D];   // [row][chunk ^ (row&15)][8]
  __shared__ int rowlist[CHUNK];
  __shared__ int wcnt[8];

  const int b = blockIdx.x;
  const int s = (b & 7) | (((b >> 3) & 1) << 3);  // same-state blocks same XCD
  const int c0 = (b >> 4) * CHUNK;
  const int tid = threadIdx.x;
  const int lane = tid & 63, w = tid >> 6;
  const int l15 = lane & 15, quad = lane >> 4;

  // ---- 1. scan chunk (loads first; ballots overlap the weight loads) ----
  const int v0 = sidx[c0 + tid];
  const int v1 = sidx[c0 + 256 + tid];

  // ---- 2. B-fragments for BOTH phases, direct fp32 -> bf16 regs ----
  // frag (kb,nb): elems A[k = kb*32 + quad*8 + j][col = w*32 + nb*16 + l15]
  short8 aW[4][2], cW[4][2];
  {
    const size_t wb = (size_t)s * D * D;
    const int col = w * 32 + l15;
#pragma unroll
    for (int kb = 0; kb < 4; kb++)
#pragma unroll
      for (int nb = 0; nb < 2; nb++) {
        const float* pA =
            A_all + wb + (size_t)(kb * 32 + quad * 8) * D + col + nb * 16;
        const float* pC =
            C_all + wb + (size_t)(kb * 32 + quad * 8) * D + col + nb * 16;
        unsigned short ta[8], tc[8];
#pragma unroll
        for (int j = 0; j < 8; j++) {
          ta[j] = f2bf(pA[j * D]);
          tc[j] = f2bf(pC[j * D]);
        }
        aW[kb][nb] = *(const short8*)ta;
        cW[kb][nb] = *(const short8*)tc;
      }
  }

  // ---- ballot compaction ----
  const unsigned long long lanelt = (1ull << lane) - 1ull;
  const unsigned long long m0 = __ballot(v0 == s);
  const unsigned long long m1 = __ballot(v1 == s);
  if (lane == 0) { wcnt[w] = (int)__popcll(m0); wcnt[4 + w] = (int)__popcll(m1); }
  __syncthreads();
  int pre0 = 0, pre1 = 0, tot0 = 0, cnt = 0;
#pragma unroll
  for (int ww = 0; ww < 4; ww++) {
    if (ww < w) { pre0 += wcnt[ww]; pre1 += wcnt[4 + ww]; }
    tot0 += wcnt[ww];
    cnt += wcnt[ww] + wcnt[4 + ww];
  }
  if (v0 == s) rowlist[pre0 + (int)__popcll(m0 & lanelt)] = c0 + tid;
  if (v1 == s) rowlist[tot0 + pre1 + (int)__popcll(m1 & lanelt)] = c0 + 256 + tid;
  if (cnt == 0) return;  // block-uniform

  // ---- 3. MFMA tiles ----
#pragma unroll 1
  for (int i0 = 0; i0 < cnt; i0 += TILE) {
    __syncthreads();  // rowlist ready (pass 0) / prior pass XH reads done

    // gather 64 X rows (4 threads/row, fp32 -> bf16), XOR-swizzled chunks
    {
      const int r = tid >> 2, q = tid & 3;
      const int rid = (i0 + r < cnt) ? rowlist[i0 + r] : -1;
      if (rid >= 0) {
        const float4* src = (const float4*)(x + (size_t)rid * D + q * 32);
#pragma unroll
        for (int i = 0; i < 4; i++) {
          float4 va = src[2 * i];
          float4 vb = src[2 * i + 1];
          *(uint4*)&XH[r * D + (((q * 4 + i) ^ (r & 15)) << 3)] = pack8(va, vb);
        }
      } else {
        uint4 z = {0, 0, 0, 0};
#pragma unroll
        for (int i = 0; i < 4; i++)
          *(uint4*)&XH[r * D + (((q * 4 + i) ^ (r & 15)) << 3)] = z;
      }
    }
    __syncthreads();  // X ready

    // phase 1: acc = X @ A ; wave w: all 64 rows, cols w*32..+31
    f32x4 acc[4][2];
#pragma unroll
    for (int ti = 0; ti < 4; ti++) {
      acc[ti][0] = (f32x4){0.f, 0.f, 0.f, 0.f};
      acc[ti][1] = (f32x4){0.f, 0.f, 0.f, 0.f};
    }
#pragma unroll
    for (int kb = 0; kb < 4; kb++) {
      short8 aF[4];
#pragma unroll
      for (int ti = 0; ti < 4; ti++)
        aF[ti] = *(const short8*)&XH[(ti * 16 + l15) * D +
                                     (((kb * 4 + quad) ^ l15) << 3)];
#pragma unroll
      for (int ti = 0; ti < 4; ti++) {
        acc[ti][0] = __builtin_amdgcn_mfma_f32_16x16x32_bf16(aF[ti], aW[kb][0],
                                                             acc[ti][0], 0, 0, 0);
        acc[ti][1] = __builtin_amdgcn_mfma_f32_16x16x32_bf16(aF[ti], aW[kb][1],
                                                             acc[ti][1], 0, 0, 0);
      }
    }
    __syncthreads();  // all phase-1 XH(X) reads done (XH reused for H)

    // H = relu(acc) -> XH, swizzle-consistent scalar writes
#pragma unroll
    for (int ti = 0; ti < 4; ti++)
#pragma unroll
      for (int nb = 0; nb < 2; nb++)
#pragma unroll
        for (int rr = 0; rr < 4; rr++) {
          float v = acc[ti][nb][rr];
          const int row = ti * 16 + quad * 4 + rr;
          const int ch = (w * 4 + nb * 2 + (l15 >> 3)) ^ (quad * 4 + rr);
          XH[row * D + (ch << 3) + (l15 & 7)] = f2bf(v > 0.f ? v : 0.f);
        }
    __syncthreads();  // H ready

    // phase 2: out = H @ C
#pragma unroll
    for (int ti = 0; ti < 4; ti++) {
      acc[ti][0] = (f32x4){0.f, 0.f, 0.f, 0.f};
      acc[ti][1] = (f32x4){0.f, 0.f, 0.f, 0.f};
    }
#pragma unroll
    for (int kb = 0; kb < 4; kb++) {
      short8 aF[4];
#pragma unroll
      for (int ti = 0; ti < 4; ti++)
        aF[ti] = *(const short8*)&XH[(ti * 16 + l15) * D +
                                     (((kb * 4 + quad) ^ l15) << 3)];
#pragma unroll
      for (int ti = 0; ti < 4; ti++) {
        acc[ti][0] = __builtin_amdgcn_mfma_f32_16x16x32_bf16(aF[ti], cW[kb][0],
                                                             acc[ti][0], 0, 0, 0);
        acc[ti][1] = __builtin_amdgcn_mfma_f32_16x16x32_bf16(aF[ti], cW[kb][1],
                                                             acc[ti][1], 0, 0, 0);
      }
    }

    // scatter stores (fp32; 16 consecutive lanes -> 64B segments)
#pragma unroll
    for (int ti = 0; ti < 4; ti++)
#pragma unroll
      for (int rr = 0; rr < 4; rr++) {
        const int rl = i0 + ti * 16 + quad * 4 + rr;
        if (rl < cnt) {
          float* orow = out + (size_t)rowlist[rl] * D + w * 32 + l15;
          orow[0] = acc[ti][0][rr];
          orow[16] = acc[ti][1][rr];
        }
      }
  }
}

extern "C" void kernel_launch(void* const* d_in, const int* in_sizes, int n_in,
                              void* d_out, int out_size, void* d_ws, size_t ws_size,
                              hipStream_t stream) {
  const float* x = (const float*)d_in[0];
  const int* sidx = (const int*)d_in[1];
  const float* A_all = (const float*)d_in[2];
  const float* C_all = (const float*)d_in[3];
  float* out = (float*)d_out;

  ssm_fused<<<512, 256, 0, stream>>>(x, sidx, A_all, C_all, out);
}